// Round 2
// baseline (461.765 us; speedup 1.0000x reference)
//
#include <hip/hip_runtime.h>

#define N_NODES 100000
#define N_EDGES 600000
#define DIM 128

typedef unsigned short ushortT;
typedef __attribute__((ext_vector_type(8))) short short8;
typedef __attribute__((ext_vector_type(4))) float float4v;
typedef __attribute__((ext_vector_type(4))) unsigned int uint4v;

__device__ __forceinline__ float bf2f(ushortT h) {
    return __builtin_bit_cast(float, ((unsigned int)h) << 16);
}
__device__ __forceinline__ float bflo(unsigned int p) {
    return __builtin_bit_cast(float, p << 16);
}
__device__ __forceinline__ float bfhi(unsigned int p) {
    return __builtin_bit_cast(float, p & 0xffff0000u);
}
__device__ __forceinline__ ushortT f2bf(float f) {  // RNE
    unsigned int x = __builtin_bit_cast(unsigned int, f);
    unsigned int r = (x + 0x7fffu + ((x >> 16) & 1u)) >> 16;
    return (ushortT)r;
}

// ---- prep: W (128x128 f32, KxN) -> transposed + XOR-swizzled bf16 hi/lo images
// element (k,n) stored at  n*128 + (((k>>3) ^ (n&15))<<3) + (k&7)
__global__ __launch_bounds__(256) void prep_kernel(const float* __restrict__ W1,
                                                   const float* __restrict__ W2,
                                                   ushortT* __restrict__ wt) {
    const float* Wf = (blockIdx.x == 0) ? W1 : W2;
    ushortT* outh = wt + blockIdx.x * 32768;
    ushortT* outl = outh + 16384;
    int t = threadIdx.x;
#pragma unroll
    for (int i = 0; i < 16; i++) {
        int c = t + i * 256;            // 0..4095
        int k = c >> 5;
        int n0 = (c & 31) * 4;
        float4v w = *(const float4v*)(Wf + k * 128 + n0);
        int g = k >> 3, kk = k & 7;
#pragma unroll
        for (int j = 0; j < 4; j++) {
            int n = n0 + j;
            ushortT wh = f2bf(w[j]);
            ushortT wl = f2bf(w[j] - bf2f(wh));
            int addr = n * 128 + ((g ^ (n & 15)) << 3) + kk;
            outh[addr] = wh;
            outl[addr] = wl;
        }
    }
}

// ---- x (f32) -> bf16 plane, once per call ----
__global__ __launch_bounds__(256) void xbf_kernel(const float* __restrict__ x,
                                                  ushortT* __restrict__ xb) {
    int i = blockIdx.x * 256 + threadIdx.x;  // 8-elem group; grid exact (6250)
    float4v a = ((const float4v*)x)[2 * i];
    float4v b = ((const float4v*)x)[2 * i + 1];
    ushortT o[8];
#pragma unroll
    for (int j = 0; j < 4; j++) o[j] = f2bf(a[j]);
#pragma unroll
    for (int j = 0; j < 4; j++) o[4 + j] = f2bf(b[j]);
    ((uint4v*)xb)[i] = *(const uint4v*)o;
}

// ---- CSR build ----
__global__ __launch_bounds__(256) void hist_kernel(const int* __restrict__ dst,
                                                   int* __restrict__ counts) {
    int e = blockIdx.x * 256 + threadIdx.x;
    if (e < N_EDGES) atomicAdd(&counts[dst[e]], 1);
}

#define SCAN_BLOCKS 98  // 98*1024 >= 100000

__global__ __launch_bounds__(1024) void blockscan_kernel(const int* __restrict__ counts,
                                                         int* __restrict__ local,
                                                         int* __restrict__ bsums) {
    __shared__ int wsum[16];
    int tid = threadIdx.x, lane = tid & 63, wid = tid >> 6;
    int i = blockIdx.x * 1024 + tid;
    int v = (i < N_NODES) ? counts[i] : 0;
    int incl = v;
#pragma unroll
    for (int off = 1; off < 64; off <<= 1) {
        int u = __shfl_up(incl, off);
        if (lane >= off) incl += u;
    }
    if (lane == 63) wsum[wid] = incl;
    __syncthreads();
    if (wid == 0) {
        int s = (lane < 16) ? wsum[lane] : 0;
#pragma unroll
        for (int off = 1; off < 16; off <<= 1) {
            int u = __shfl_up(s, off);
            if (lane >= off) s += u;
        }
        if (lane < 16) wsum[lane] = s;
    }
    __syncthreads();
    int excl = ((wid == 0) ? 0 : wsum[wid - 1]) + incl - v;
    if (i < N_NODES) local[i] = excl;
    if (tid == 0) bsums[blockIdx.x] = wsum[15];
}

__global__ __launch_bounds__(1024) void fixup_kernel(const int* __restrict__ local,
                                                     const int* __restrict__ bsums,
                                                     int* __restrict__ offsets,
                                                     int* __restrict__ cursor) {
    __shared__ int sbase;
    int tid = threadIdx.x;
    if (tid < 64) {
        int s = 0;
        for (int j = tid; j < blockIdx.x; j += 64) s += bsums[j];
#pragma unroll
        for (int off = 32; off >= 1; off >>= 1) s += __shfl_xor(s, off);
        if (tid == 0) sbase = s;
    }
    __syncthreads();
    int base = sbase;
    int i = blockIdx.x * 1024 + tid;
    if (i < N_NODES) {
        int o = local[i] + base;
        offsets[i] = o;
        cursor[i] = o;
    }
    if (blockIdx.x == 0 && tid == 0) offsets[N_NODES] = N_EDGES;
}

__global__ __launch_bounds__(256) void fill_kernel(const int* __restrict__ src,
                                                   const int* __restrict__ dst,
                                                   int* __restrict__ cursor,
                                                   int* __restrict__ eidx) {
    int e = blockIdx.x * 256 + threadIdx.x;
    if (e < N_EDGES) {
        int pos = atomicAdd(&cursor[dst[e]], 1);
        eidx[pos] = src[e];
    }
}

// ---- aggregation: one wave per node; z[v] = h[v] + sum neighbors (h is bf16 plane).
// Output: interleaved bf16 hi/lo planes, node stride 256 ushorts (hi +0, lo +128).
__global__ __launch_bounds__(256) void agg_kernel(const ushortT* __restrict__ h,
                                                  const int* __restrict__ offsets,
                                                  const int* __restrict__ eidx,
                                                  ushortT* __restrict__ z) {
    int w = blockIdx.x * 4 + (threadIdx.x >> 6);  // node id; grid exact (25000 blocks)
    w = __builtin_amdgcn_readfirstlane(w);
    int lane = threadIdx.x & 63;
    const ushortT* hp = h + lane * 2;
    int beg = offsets[w], end = offsets[w + 1];
    int cnt = end - beg;
    unsigned int p0 = *(const unsigned int*)(hp + (size_t)w * DIM);
    float ax = bflo(p0), ay = bfhi(p0);
    for (int base = 0; base < cnt; base += 8) {
        int idx[8];
#pragma unroll
        for (int j = 0; j < 8; j++) {
            int q = base + j;
            if (q > cnt - 1) q = cnt - 1;
            idx[j] = eidx[beg + q];
        }
        unsigned int v[8];
#pragma unroll
        for (int j = 0; j < 8; j++) v[j] = *(const unsigned int*)(hp + (size_t)idx[j] * DIM);
        int rem = cnt - base;  // wave-uniform
#pragma unroll
        for (int j = 0; j < 8; j++)
            if (j < rem) { ax += bflo(v[j]); ay += bfhi(v[j]); }
    }
    ushortT hx = f2bf(ax), hy = f2bf(ay);
    float lx = ax - bf2f(hx), ly = ay - bf2f(hy);
    unsigned int hi = (unsigned int)hx | ((unsigned int)hy << 16);
    unsigned int lo = (unsigned int)f2bf(lx) | ((unsigned int)f2bf(ly) << 16);
    *(unsigned int*)(z + (size_t)w * 256 + lane * 2)       = hi;
    *(unsigned int*)(z + (size_t)w * 256 + 128 + lane * 2) = lo;
}

// lgkm-only wait: vmcnt=63, expcnt=7, lgkmcnt=0  (gfx9 encoding)
#define LGKM0() __builtin_amdgcn_s_waitcnt(0xC07F)

__device__ __forceinline__ void load_A(const ushortT* __restrict__ A, int row0, int col16,
                                       int quad, short8 (&ah)[4][2], short8 (&al)[4][2]) {
#pragma unroll
    for (int r = 0; r < 2; r++) {
        const ushortT* ap = A + (size_t)(row0 + r * 16 + col16) * 256 + quad * 8;
#pragma unroll
        for (int s = 0; s < 4; s++) {
            ah[s][r] = *(const short8*)(ap + s * 32);
            al[s][r] = *(const short8*)(ap + s * 32 + 128);
        }
    }
}

// ---- persistent fused MLP: out = act(relu(A @ W1 + b1) @ W2 + b2) ----
// 512 threads (8 waves), grid 256 (1 block/CU). LDS 144KB:
//   [0,16384)  W1H   [16384,32768) W1L   [32768,49152) W2H   [49152,65536) W2L
//   [65536,73728) per-wave 1024-ushort transpose scratch (16 rows x 64, XOR-swizzled)
// One __syncthreads after W staging; afterwards every wave is fully independent:
// no barriers, lgkm-only waits, so in-flight global loads survive the transpose.
// Each wave handles units {g, g+2048} (g = bid*8+wid, 3125 units); the second
// unit's A loads are issued before the first unit's epilogue (latency hidden
// under stores + next B-frag reads). Epilogue: direct 2B/4B global stores
// (4x32B / 4x64B segments per instr; L2 merges into full lines).
// Numerics bit-identical to the previous two-kernel path.
// OUT 1: bf16 plane (stride 128) + relu. OUT 2: f32 (stride 128), no relu
// (layer 2: A==out alias row-for-row; each wave reads only its own rows into
// regs before storing them, and prefetch rows are disjoint from stored rows).
template <int OUT>
__global__ __launch_bounds__(512, 2) void mlp_kernel(const ushortT* __restrict__ A,
                                                     const ushortT* __restrict__ wtAll,
                                                     const float* __restrict__ b1,
                                                     const float* __restrict__ b2,
                                                     void* __restrict__ out) {
    __shared__ ushortT SH[73728];  // 144KB

    int t = threadIdx.x, lane = t & 63, wid = t >> 6;
    int quad = lane >> 4, col16 = lane & 15;

    float bia1[8], bia2[8];
#pragma unroll
    for (int n = 0; n < 8; n++) {
        bia1[n] = b1[n * 16 + col16];
        bia2[n] = b2[n * 16 + col16];
    }

    int u = blockIdx.x * 8 + wid;  // 0..2047, all < 3125
    int row0 = u * 32;
    bool more = (u + 2048) < (N_NODES / 32);

    // first unit's A loads: in flight across the staging barrier
    short8 ah[4][2], al[4][2];
    load_A(A, row0, col16, quad, ah, al);

    // stage W1H|W1L|W2H|W2L (128KB) cooperatively, once
#pragma unroll
    for (int i = 0; i < 16; i++) {
        int idx = (t + i * 512) * 8;
        *(uint4v*)&SH[idx] = *(const uint4v*)&wtAll[idx];
    }
    __syncthreads();

    ushortT* scr = &SH[65536 + wid * 1024];  // 16 rows x 64 ushorts, XOR-swizzled

#pragma unroll
    for (int uu = 0; uu < 2; ++uu) {
        // ---- GEMM1: acc = A @ W1 (3-term bf16 split) ----
        float4v acc[2][8];
#pragma unroll
        for (int r = 0; r < 2; r++)
#pragma unroll
            for (int n = 0; n < 8; n++) acc[r][n] = (float4v)0.0f;
#pragma unroll
        for (int s = 0; s < 4; s++) {
            short8 bh[8], bl[8];
#pragma unroll
            for (int n = 0; n < 8; n++) {
                int addr = (n * 16 + col16) * 128 + (((s * 4 + quad) ^ col16) << 3);
                bh[n] = *(const short8*)&SH[addr];
                bl[n] = *(const short8*)&SH[16384 + addr];
            }
#pragma unroll
            for (int r = 0; r < 2; r++)
#pragma unroll
                for (int n = 0; n < 8; n++) {
                    acc[r][n] = __builtin_amdgcn_mfma_f32_16x16x32_bf16(ah[s][r], bh[n], acc[r][n], 0, 0, 0);
                    acc[r][n] = __builtin_amdgcn_mfma_f32_16x16x32_bf16(al[s][r], bh[n], acc[r][n], 0, 0, 0);
                    acc[r][n] = __builtin_amdgcn_mfma_f32_16x16x32_bf16(ah[s][r], bl[n], acc[r][n], 0, 0, 0);
                }
        }

        // ---- transpose (per-wave scratch, two 16-row halves) + GEMM2 ----
        float4v acc2[2][8];
#pragma unroll
        for (int r = 0; r < 2; r++)
#pragma unroll
            for (int n = 0; n < 8; n++) acc2[r][n] = (float4v)0.0f;
#pragma unroll
        for (int s2 = 0; s2 < 4; s2++) {
            short8 a2h[2], a2l[2];
#pragma unroll
            for (int r = 0; r < 2; r++) {
                LGKM0();  // WAR: prior scratch reads landed before overwrite
#pragma unroll
                for (int h = 0; h < 2; h++) {
                    int n = s2 * 2 + h;
#pragma unroll
                    for (int i = 0; i < 4; i++) {
                        float v = acc[r][n][i] + bia1[n];
                        v = v > 0.0f ? v : 0.0f;
                        int row = quad * 4 + i;  // local row in this 16-row half
                        ushortT hi = f2bf(v);
                        ushortT lo = f2bf(v - bf2f(hi));
                        int c8 = h * 2 + (col16 >> 3);
                        int base = row * 64 + (col16 & 7);
                        scr[base + ((c8 ^ (row & 7)) << 3)]       = hi;
                        scr[base + (((4 + c8) ^ (row & 7)) << 3)] = lo;
                    }
                }
                LGKM0();  // writes visible before readback (per-wave scratch)
                int rrow = col16;
                a2h[r] = *(const short8*)&scr[rrow * 64 + ((quad ^ (rrow & 7)) << 3)];
                a2l[r] = *(const short8*)&scr[rrow * 64 + (((4 + quad) ^ (rrow & 7)) << 3)];
            }
            short8 bh[8], bl[8];
#pragma unroll
            for (int n = 0; n < 8; n++) {
                int addr = (n * 16 + col16) * 128 + (((s2 * 4 + quad) ^ col16) << 3);
                bh[n] = *(const short8*)&SH[32768 + addr];
                bl[n] = *(const short8*)&SH[49152 + addr];
            }
#pragma unroll
            for (int r = 0; r < 2; r++)
#pragma unroll
                for (int n = 0; n < 8; n++) {
                    acc2[r][n] = __builtin_amdgcn_mfma_f32_16x16x32_bf16(a2h[r], bh[n], acc2[r][n], 0, 0, 0);
                    acc2[r][n] = __builtin_amdgcn_mfma_f32_16x16x32_bf16(a2l[r], bh[n], acc2[r][n], 0, 0, 0);
                    acc2[r][n] = __builtin_amdgcn_mfma_f32_16x16x32_bf16(a2h[r], bl[n], acc2[r][n], 0, 0, 0);
                }
        }

        // prefetch next unit's A (ah/al dead) before the epilogue: latency hides
        // under the stores + next GEMM1's B-frag reads
        if (uu == 0 && more) load_A(A, (u + 2048) * 32, col16, quad, ah, al);

        // ---- epilogue: direct global stores (no LDS) ----
        // C/D layout: col = n*16+col16, row = r*16 + quad*4 + i
#pragma unroll
        for (int r = 0; r < 2; r++) {
#pragma unroll
            for (int n = 0; n < 8; n++)
#pragma unroll
                for (int i = 0; i < 4; i++) {
                    float v = acc2[r][n][i] + bia2[n];
                    size_t off = (size_t)(row0 + r * 16 + quad * 4 + i) * 128 + n * 16 + col16;
                    if constexpr (OUT == 1) {
                        v = v > 0.0f ? v : 0.0f;
                        ((ushortT*)out)[off] = f2bf(v);
                    } else {
                        ((float*)out)[off] = v;
                    }
                }
        }

        if (uu == 0) {
            if (!more) break;
            row0 = (u + 2048) * 32;
        }
    }
}

extern "C" void kernel_launch(void* const* d_in, const int* in_sizes, int n_in,
                              void* d_out, int out_size, void* d_ws, size_t ws_size,
                              hipStream_t stream) {
    const float* x  = (const float*)d_in[0];
    const int* src  = (const int*)d_in[1];
    const int* dst  = (const int*)d_in[2];
    const float* W1 = (const float*)d_in[3];
    const float* b1 = (const float*)d_in[4];
    const float* W2 = (const float*)d_in[5];
    const float* b2 = (const float*)d_in[6];

    ushortT* zbuf = (ushortT*)d_out;  // d_out doubles as interleaved bf16 z (51.2MB)

    char* ws = (char*)d_ws;
    ushortT* wt     = (ushortT*)ws;                        // 128 KB: W1H|W1L|W2H|W2L (swizzled)
    int*     offs   = (int*)(ws + 131072);                 // 100001 ints
    int*     cursor = (int*)(ws + 531456);                 // 100000 ints
    int*     eidx   = (int*)(ws + 931456);                 // 600000 ints
    int*     local  = (int*)(ws + 3331456);                // 100000 ints
    int*     bsums  = (int*)(ws + 3731456);                // 98 ints
    ushortT* xbf    = (ushortT*)(ws + 3731968);            // 25.6 MB bf16 x
    ushortT* hbf    = (ushortT*)(ws + 3731968 + 25600000); // 25.6 MB bf16 h
    // total ~55 MB

    dim3 blk(256);
    const int gEdge = (N_EDGES + 255) / 256;    // 2344
    const int gAgg  = N_NODES / 4;              // 25000 exact (1 wave/node)
    const int gXbf  = N_NODES * DIM / 8 / 256;  // 6250 exact
    const int gMlp  = 256;                      // persistent: 1 block/CU, 8 waves

    prep_kernel<<<2, blk, 0, stream>>>(W1, W2, wt);
    xbf_kernel<<<gXbf, blk, 0, stream>>>(x, xbf);
    hipMemsetAsync(cursor, 0, N_NODES * sizeof(int), stream);
    hist_kernel<<<gEdge, blk, 0, stream>>>(dst, cursor);
    blockscan_kernel<<<SCAN_BLOCKS, 1024, 0, stream>>>(cursor, local, bsums);
    fixup_kernel<<<SCAN_BLOCKS, 1024, 0, stream>>>(local, bsums, offs, cursor);
    fill_kernel<<<gEdge, blk, 0, stream>>>(src, dst, cursor, eidx);

    // layer 0
    agg_kernel<<<gAgg, blk, 0, stream>>>(xbf, offs, eidx, zbuf);
    mlp_kernel<1><<<gMlp, 512, 0, stream>>>(zbuf, wt, b1, b2, hbf);
    // layer 1
    agg_kernel<<<gAgg, blk, 0, stream>>>(hbf, offs, eidx, zbuf);
    mlp_kernel<1><<<gMlp, 512, 0, stream>>>(zbuf, wt, b1, b2, hbf);
    // layer 2 (final: f32 to d_out, no relu; z aliases d_out row-for-row, wave-local)
    agg_kernel<<<gAgg, blk, 0, stream>>>(hbf, offs, eidx, zbuf);
    mlp_kernel<2><<<gMlp, 512, 0, stream>>>(zbuf, wt, b1, b2, (float*)d_out);
}

// Round 3
// 393.930 us; speedup vs baseline: 1.1722x; 1.1722x over previous
//
#include <hip/hip_runtime.h>

#define N_NODES 100000
#define N_EDGES 600000
#define DIM 128

typedef unsigned short ushortT;
typedef __attribute__((ext_vector_type(8))) short short8;
typedef __attribute__((ext_vector_type(4))) float float4v;
typedef __attribute__((ext_vector_type(4))) unsigned int uint4v;

__device__ __forceinline__ float bf2f(ushortT h) {
    return __builtin_bit_cast(float, ((unsigned int)h) << 16);
}
__device__ __forceinline__ float bflo(unsigned int p) {
    return __builtin_bit_cast(float, p << 16);
}
__device__ __forceinline__ float bfhi(unsigned int p) {
    return __builtin_bit_cast(float, p & 0xffff0000u);
}
__device__ __forceinline__ ushortT f2bf(float f) {  // RNE
    unsigned int x = __builtin_bit_cast(unsigned int, f);
    unsigned int r = (x + 0x7fffu + ((x >> 16) & 1u)) >> 16;
    return (ushortT)r;
}

// ---- prep: W (128x128 f32, KxN) -> transposed + XOR-swizzled bf16 hi/lo images
// element (k,n) stored at  n*128 + (((k>>3) ^ (n&15))<<3) + (k&7)
__global__ __launch_bounds__(256) void prep_kernel(const float* __restrict__ W1,
                                                   const float* __restrict__ W2,
                                                   ushortT* __restrict__ wt) {
    const float* Wf = (blockIdx.x == 0) ? W1 : W2;
    ushortT* outh = wt + blockIdx.x * 32768;
    ushortT* outl = outh + 16384;
    int t = threadIdx.x;
#pragma unroll
    for (int i = 0; i < 16; i++) {
        int c = t + i * 256;            // 0..4095
        int k = c >> 5;
        int n0 = (c & 31) * 4;
        float4v w = *(const float4v*)(Wf + k * 128 + n0);
        int g = k >> 3, kk = k & 7;
#pragma unroll
        for (int j = 0; j < 4; j++) {
            int n = n0 + j;
            ushortT wh = f2bf(w[j]);
            ushortT wl = f2bf(w[j] - bf2f(wh));
            int addr = n * 128 + ((g ^ (n & 15)) << 3) + kk;
            outh[addr] = wh;
            outl[addr] = wl;
        }
    }
}

// ---- x (f32) -> bf16 plane, once per call ----
__global__ __launch_bounds__(256) void xbf_kernel(const float* __restrict__ x,
                                                  ushortT* __restrict__ xb) {
    int i = blockIdx.x * 256 + threadIdx.x;  // 8-elem group; grid exact (6250)
    float4v a = ((const float4v*)x)[2 * i];
    float4v b = ((const float4v*)x)[2 * i + 1];
    ushortT o[8];
#pragma unroll
    for (int j = 0; j < 4; j++) o[j] = f2bf(a[j]);
#pragma unroll
    for (int j = 0; j < 4; j++) o[4 + j] = f2bf(b[j]);
    ((uint4v*)xb)[i] = *(const uint4v*)o;
}

// ---- CSR build ----
__global__ __launch_bounds__(256) void hist_kernel(const int* __restrict__ dst,
                                                   int* __restrict__ counts) {
    int e = blockIdx.x * 256 + threadIdx.x;
    if (e < N_EDGES) atomicAdd(&counts[dst[e]], 1);
}

#define SCAN_BLOCKS 98  // 98*1024 >= 100000

__global__ __launch_bounds__(1024) void blockscan_kernel(const int* __restrict__ counts,
                                                         int* __restrict__ local,
                                                         int* __restrict__ bsums) {
    __shared__ int wsum[16];
    int tid = threadIdx.x, lane = tid & 63, wid = tid >> 6;
    int i = blockIdx.x * 1024 + tid;
    int v = (i < N_NODES) ? counts[i] : 0;
    int incl = v;
#pragma unroll
    for (int off = 1; off < 64; off <<= 1) {
        int u = __shfl_up(incl, off);
        if (lane >= off) incl += u;
    }
    if (lane == 63) wsum[wid] = incl;
    __syncthreads();
    if (wid == 0) {
        int s = (lane < 16) ? wsum[lane] : 0;
#pragma unroll
        for (int off = 1; off < 16; off <<= 1) {
            int u = __shfl_up(s, off);
            if (lane >= off) s += u;
        }
        if (lane < 16) wsum[lane] = s;
    }
    __syncthreads();
    int excl = ((wid == 0) ? 0 : wsum[wid - 1]) + incl - v;
    if (i < N_NODES) local[i] = excl;
    if (tid == 0) bsums[blockIdx.x] = wsum[15];
}

__global__ __launch_bounds__(1024) void fixup_kernel(const int* __restrict__ local,
                                                     const int* __restrict__ bsums,
                                                     int* __restrict__ offsets,
                                                     int* __restrict__ cursor) {
    __shared__ int sbase;
    int tid = threadIdx.x;
    if (tid < 64) {
        int s = 0;
        for (int j = tid; j < blockIdx.x; j += 64) s += bsums[j];
#pragma unroll
        for (int off = 32; off >= 1; off >>= 1) s += __shfl_xor(s, off);
        if (tid == 0) sbase = s;
    }
    __syncthreads();
    int base = sbase;
    int i = blockIdx.x * 1024 + tid;
    if (i < N_NODES) {
        int o = local[i] + base;
        offsets[i] = o;
        cursor[i] = o;
    }
    if (blockIdx.x == 0 && tid == 0) offsets[N_NODES] = N_EDGES;
}

__global__ __launch_bounds__(256) void fill_kernel(const int* __restrict__ src,
                                                   const int* __restrict__ dst,
                                                   int* __restrict__ cursor,
                                                   int* __restrict__ eidx) {
    int e = blockIdx.x * 256 + threadIdx.x;
    if (e < N_EDGES) {
        int pos = atomicAdd(&cursor[dst[e]], 1);
        eidx[pos] = src[e];
    }
}

// ---- aggregation: one wave per node; z[v] = h[v] + sum neighbors (h is bf16 plane).
// Output: interleaved bf16 hi/lo planes, node stride 256 ushorts (hi +0, lo +128).
__global__ __launch_bounds__(256) void agg_kernel(const ushortT* __restrict__ h,
                                                  const int* __restrict__ offsets,
                                                  const int* __restrict__ eidx,
                                                  ushortT* __restrict__ z) {
    int w = blockIdx.x * 4 + (threadIdx.x >> 6);  // node id; grid exact (25000 blocks)
    w = __builtin_amdgcn_readfirstlane(w);
    int lane = threadIdx.x & 63;
    const ushortT* hp = h + lane * 2;
    int beg = offsets[w], end = offsets[w + 1];
    int cnt = end - beg;
    unsigned int p0 = *(const unsigned int*)(hp + (size_t)w * DIM);
    float ax = bflo(p0), ay = bfhi(p0);
    for (int base = 0; base < cnt; base += 8) {
        int idx[8];
#pragma unroll
        for (int j = 0; j < 8; j++) {
            int q = base + j;
            if (q > cnt - 1) q = cnt - 1;
            idx[j] = eidx[beg + q];
        }
        unsigned int v[8];
#pragma unroll
        for (int j = 0; j < 8; j++) v[j] = *(const unsigned int*)(hp + (size_t)idx[j] * DIM);
        int rem = cnt - base;  // wave-uniform
#pragma unroll
        for (int j = 0; j < 8; j++)
            if (j < rem) { ax += bflo(v[j]); ay += bfhi(v[j]); }
    }
    ushortT hx = f2bf(ax), hy = f2bf(ay);
    float lx = ax - bf2f(hx), ly = ay - bf2f(hy);
    unsigned int hi = (unsigned int)hx | ((unsigned int)hy << 16);
    unsigned int lo = (unsigned int)f2bf(lx) | ((unsigned int)f2bf(ly) << 16);
    *(unsigned int*)(z + (size_t)w * 256 + lane * 2)       = hi;
    *(unsigned int*)(z + (size_t)w * 256 + 128 + lane * 2) = lo;
}

// lgkm-only wait: vmcnt=63, expcnt=7, lgkmcnt=0 (gfx9 encoding: [3:0]|[15:14]=vm, [6:4]=exp, [11:8]=lgkm)
#define LGKM0() __builtin_amdgcn_s_waitcnt(0xC07F)

// ---- fused MLP: out = act(relu(A @ W1 + b1) @ W2 + b2) ----
// Round-1 structure (4 waves, 80KB LDS, 2 blocks/CU — reg cap 244 => 2 waves/SIMD).
// Round-3 additions: (1) block-uniform K-phase rotation <ROT> so co-resident blocks
// desync their GEMM/transpose phases (the 2 waves/SIMD were phase-locked, stalling
// together); (2) s_setprio(1) around MFMA bursts (T5 — pays once phases diverge);
// (3) lgkm-only waits so global stores are never drained.
// OUT 1: bf16 plane (stride 128) + relu. OUT 2: f32 (stride 128), no relu.
// Layer-2: A(=zbuf)==out(=d_out) alias row-for-row; block reads its 32 rows into
// regs before the first barrier and stores after the last -> safe.
template <int OUT, int ROT>
__device__ __forceinline__ void mlp_body(ushortT* SH,
                                         const ushortT* __restrict__ A,
                                         const ushortT* __restrict__ w1HL,
                                         const ushortT* __restrict__ w2HL,
                                         const float* __restrict__ b1,
                                         const float* __restrict__ b2,
                                         void* __restrict__ out) {
    int t = threadIdx.x, lane = t & 63, wid = t >> 6;
    int unit = blockIdx.x * 4 + wid;  // 32-row unit; 3125 total
    int quad = lane >> 4, col16 = lane & 15;
    bool active = unit < (N_NODES / 32);
    int row0 = unit * 32;

    float bia1[8], bia2[8];
#pragma unroll
    for (int n = 0; n < 8; n++) {
        bia1[n] = b1[n * 16 + col16];
        bia2[n] = b2[n * 16 + col16];
    }

    // A prefetch: 32 independent b128 loads (issued before staging, covered by barrier)
    short8 ah[4][2], al[4][2];
    if (active) {
#pragma unroll
        for (int r = 0; r < 2; r++) {
            const ushortT* ap = A + (size_t)(row0 + r * 16 + col16) * 256 + quad * 8;
#pragma unroll
            for (int s = 0; s < 4; s++) {
                ah[s][r] = *(const short8*)(ap + s * 32);
                al[s][r] = *(const short8*)(ap + s * 32 + 128);
            }
        }
    }

    // stage W1 images: coalesced b128
#pragma unroll
    for (int i = 0; i < 16; i++) {
        int idx = (t + i * 256) * 8;
        *(uint4v*)&SH[idx] = *(const uint4v*)&w1HL[idx];
    }
    __syncthreads();

    float4v acc[2][8];
    if (active) {
#pragma unroll
        for (int r = 0; r < 2; r++)
#pragma unroll
            for (int n = 0; n < 8; n++) acc[r][n] = (float4v)0.0f;
#pragma unroll
        for (int ss = 0; ss < 4; ss++) {
            const int s = (ss + ROT) & 3;  // folds: ROT is a template constant, ss unrolled
            // batch all 16 B-frag LDS reads -> single wait, then MFMA burst
            short8 bh[8], bl[8];
#pragma unroll
            for (int n = 0; n < 8; n++) {
                int addr = (n * 16 + col16) * 128 + (((s * 4 + quad) ^ col16) << 3);
                bh[n] = *(const short8*)&SH[addr];
                bl[n] = *(const short8*)&SH[16384 + addr];
            }
            __builtin_amdgcn_s_setprio(1);
#pragma unroll
            for (int r = 0; r < 2; r++)
#pragma unroll
                for (int n = 0; n < 8; n++) {
                    acc[r][n] = __builtin_amdgcn_mfma_f32_16x16x32_bf16(ah[s][r], bh[n], acc[r][n], 0, 0, 0);
                    acc[r][n] = __builtin_amdgcn_mfma_f32_16x16x32_bf16(al[s][r], bh[n], acc[r][n], 0, 0, 0);
                    acc[r][n] = __builtin_amdgcn_mfma_f32_16x16x32_bf16(ah[s][r], bl[n], acc[r][n], 0, 0, 0);
                }
            __builtin_amdgcn_s_setprio(0);
        }
    }
    __syncthreads();  // all waves done reading W1

    // restage W2 over the dead W1 region (L2-hit, 64KB/block)
#pragma unroll
    for (int i = 0; i < 16; i++) {
        int idx = (t + i * 256) * 8;
        *(uint4v*)&SH[idx] = *(const uint4v*)&w2HL[idx];
    }
    __syncthreads();

    float4v acc2[2][8];
    if (active) {
#pragma unroll
        for (int r = 0; r < 2; r++)
#pragma unroll
            for (int n = 0; n < 8; n++) acc2[r][n] = (float4v)0.0f;
        ushortT* scr = &SH[32768 + wid * 2048];  // 32 rows x 64 ushorts (hi 0..31, lo 32..63), XOR-swizzled
#pragma unroll
        for (int ss = 0; ss < 4; ss++) {
            const int s2 = (ss + ROT) & 3;
            LGKM0();  // WAR: prior s2's scratch reads landed before overwrite (lgkm-only)
            // transpose-write hid cols [32*s2, 32*s2+32): bias+relu, RNE hi/lo split
#pragma unroll
            for (int r = 0; r < 2; r++)
#pragma unroll
                for (int h = 0; h < 2; h++) {
                    int n = s2 * 2 + h;
#pragma unroll
                    for (int i = 0; i < 4; i++) {
                        float v = acc[r][n][i] + bia1[n];
                        v = v > 0.0f ? v : 0.0f;
                        int row = r * 16 + quad * 4 + i;
                        ushortT hi = f2bf(v);
                        ushortT lo = f2bf(v - bf2f(hi));
                        int c8 = h * 2 + (col16 >> 3);
                        int base = row * 64 + (col16 & 7);
                        scr[base + ((c8 ^ (row & 7)) << 3)]       = hi;
                        scr[base + (((4 + c8) ^ (row & 7)) << 3)] = lo;
                    }
                }
            LGKM0();  // writes visible before readback (per-wave scratch)
            short8 a2h[2], a2l[2];
#pragma unroll
            for (int r = 0; r < 2; r++) {
                int rrow = r * 16 + col16;
                a2h[r] = *(const short8*)&scr[rrow * 64 + ((quad ^ (rrow & 7)) << 3)];
                a2l[r] = *(const short8*)&scr[rrow * 64 + (((4 + quad) ^ (rrow & 7)) << 3)];
            }
            short8 bh[8], bl[8];
#pragma unroll
            for (int n = 0; n < 8; n++) {
                int addr = (n * 16 + col16) * 128 + (((s2 * 4 + quad) ^ col16) << 3);
                bh[n] = *(const short8*)&SH[addr];
                bl[n] = *(const short8*)&SH[16384 + addr];
            }
            __builtin_amdgcn_s_setprio(1);
#pragma unroll
            for (int r = 0; r < 2; r++)
#pragma unroll
                for (int n = 0; n < 8; n++) {
                    acc2[r][n] = __builtin_amdgcn_mfma_f32_16x16x32_bf16(a2h[r], bh[n], acc2[r][n], 0, 0, 0);
                    acc2[r][n] = __builtin_amdgcn_mfma_f32_16x16x32_bf16(a2l[r], bh[n], acc2[r][n], 0, 0, 0);
                    acc2[r][n] = __builtin_amdgcn_mfma_f32_16x16x32_bf16(a2h[r], bl[n], acc2[r][n], 0, 0, 0);
                }
            __builtin_amdgcn_s_setprio(0);
        }
    }
    __syncthreads();  // W region dead after all waves' K-loops
    if (!active) return;

    // epilogue: C/D layout col=lane&15 (within n-block), row=quad*4+i.
    // Two 16-row passes through per-wave LDS scratch -> coalesced stores.
#pragma unroll
    for (int r = 0; r < 2; r++) {
        if constexpr (OUT == 1) {
            ushortT* tr = &SH[wid * 2304];
#pragma unroll
            for (int n = 0; n < 8; n++)
#pragma unroll
                for (int i = 0; i < 4; i++) {
                    float v = acc2[r][n][i] + bia2[n];
                    v = v > 0.0f ? v : 0.0f;
                    tr[(quad * 4 + i) * 136 + n * 16 + col16] = f2bf(v);
                }
            LGKM0();
#pragma unroll
            for (int p = 0; p < 4; p++) {
                int row = p * 4 + (lane >> 4);
                int seg = lane & 15;
                uint4v val = *(const uint4v*)&tr[row * 136 + seg * 8];
                *(uint4v*)((ushortT*)out + (size_t)(row0 + r * 16 + row) * 128 + seg * 8) = val;
            }
        } else {
            float* trf = (float*)&SH[wid * 4352];  // stride 132 floats
#pragma unroll
            for (int n = 0; n < 8; n++)
#pragma unroll
                for (int i = 0; i < 4; i++)
                    trf[(quad * 4 + i) * 132 + n * 16 + col16] = acc2[r][n][i] + bia2[n];
            LGKM0();
#pragma unroll
            for (int p = 0; p < 8; p++) {
                int row = p * 2 + (lane >> 5);
                int seg = lane & 31;
                float4v val = *(const float4v*)&trf[row * 132 + seg * 4];
                *(float4v*)((float*)out + (size_t)(row0 + r * 16 + row) * 128 + seg * 4) = val;
            }
        }
        if (r == 0) LGKM0();  // WAR guard before pass 2 overwrite (lgkm-only: stores keep flying)
    }
}

template <int OUT>
__global__ __launch_bounds__(256, 2) void mlp_kernel(const ushortT* __restrict__ A,
                                                     const ushortT* __restrict__ w1HL,
                                                     const ushortT* __restrict__ w2HL,
                                                     const float* __restrict__ b1,
                                                     const float* __restrict__ b2,
                                                     void* __restrict__ out) {
    __shared__ ushortT SH[40960];  // 80KB: W image [0,32768), transpose scratch [32768,40960)
    // block-uniform phase rotation: co-resident blocks (bid, ~bid+256) get different
    // K-phase start so the 2 waves/SIMD stop stalling in lockstep
    unsigned bid = blockIdx.x;
    if ((bid ^ (bid >> 8)) & 1)
        mlp_body<OUT, 2>(SH, A, w1HL, w2HL, b1, b2, out);
    else
        mlp_body<OUT, 0>(SH, A, w1HL, w2HL, b1, b2, out);
}

extern "C" void kernel_launch(void* const* d_in, const int* in_sizes, int n_in,
                              void* d_out, int out_size, void* d_ws, size_t ws_size,
                              hipStream_t stream) {
    const float* x  = (const float*)d_in[0];
    const int* src  = (const int*)d_in[1];
    const int* dst  = (const int*)d_in[2];
    const float* W1 = (const float*)d_in[3];
    const float* b1 = (const float*)d_in[4];
    const float* W2 = (const float*)d_in[5];
    const float* b2 = (const float*)d_in[6];

    ushortT* zbuf = (ushortT*)d_out;  // d_out doubles as interleaved bf16 z (51.2MB)

    char* ws = (char*)d_ws;
    ushortT* wt     = (ushortT*)ws;                        // 128 KB: W1H|W1L|W2H|W2L (swizzled)
    int*     offs   = (int*)(ws + 131072);                 // 100001 ints
    int*     cursor = (int*)(ws + 531456);                 // 100000 ints
    int*     eidx   = (int*)(ws + 931456);                 // 600000 ints
    int*     local  = (int*)(ws + 3331456);                // 100000 ints
    int*     bsums  = (int*)(ws + 3731456);                // 98 ints
    ushortT* xbf    = (ushortT*)(ws + 3731968);            // 25.6 MB bf16 x
    ushortT* hbf    = (ushortT*)(ws + 3731968 + 25600000); // 25.6 MB bf16 h
    // total ~55 MB

    const ushortT* w1 = wt;          // WH at +0, WL at +16384
    const ushortT* w2 = wt + 32768;  // WH at +0, WL at +16384

    dim3 blk(256);
    const int gEdge = (N_EDGES + 255) / 256;    // 2344
    const int gAgg  = N_NODES / 4;              // 25000 exact (1 wave/node)
    const int gGemm = (N_NODES / 32 + 3) / 4;   // 782 (3125 32-row units)
    const int gXbf  = N_NODES * DIM / 8 / 256;  // 6250 exact

    prep_kernel<<<2, blk, 0, stream>>>(W1, W2, wt);
    xbf_kernel<<<gXbf, blk, 0, stream>>>(x, xbf);
    hipMemsetAsync(cursor, 0, N_NODES * sizeof(int), stream);
    hist_kernel<<<gEdge, blk, 0, stream>>>(dst, cursor);
    blockscan_kernel<<<SCAN_BLOCKS, 1024, 0, stream>>>(cursor, local, bsums);
    fixup_kernel<<<SCAN_BLOCKS, 1024, 0, stream>>>(local, bsums, offs, cursor);
    fill_kernel<<<gEdge, blk, 0, stream>>>(src, dst, cursor, eidx);

    // layer 0
    agg_kernel<<<gAgg, blk, 0, stream>>>(xbf, offs, eidx, zbuf);
    mlp_kernel<1><<<gGemm, blk, 0, stream>>>(zbuf, w1, w2, b1, b2, hbf);
    // layer 1
    agg_kernel<<<gAgg, blk, 0, stream>>>(hbf, offs, eidx, zbuf);
    mlp_kernel<1><<<gGemm, blk, 0, stream>>>(zbuf, w1, w2, b1, b2, hbf);
    // layer 2 (final: f32 to d_out, no relu; z aliases d_out row-for-row, wave-local)
    agg_kernel<<<gAgg, blk, 0, stream>>>(hbf, offs, eidx, zbuf);
    mlp_kernel<2><<<gGemm, blk, 0, stream>>>(zbuf, w1, w2, b1, b2, (float*)d_out);
}

// Round 4
// 391.300 us; speedup vs baseline: 1.1801x; 1.0067x over previous
//
#include <hip/hip_runtime.h>

#define N_NODES 100000
#define N_EDGES 600000
#define DIM 128

typedef unsigned short ushortT;
typedef __attribute__((ext_vector_type(8))) short short8;
typedef __attribute__((ext_vector_type(4))) float float4v;
typedef __attribute__((ext_vector_type(4))) unsigned int uint4v;

__device__ __forceinline__ float bf2f(ushortT h) {
    return __builtin_bit_cast(float, ((unsigned int)h) << 16);
}
__device__ __forceinline__ float bflo(unsigned int p) {
    return __builtin_bit_cast(float, p << 16);
}
__device__ __forceinline__ float bfhi(unsigned int p) {
    return __builtin_bit_cast(float, p & 0xffff0000u);
}
__device__ __forceinline__ ushortT f2bf(float f) {  // RNE
    unsigned int x = __builtin_bit_cast(unsigned int, f);
    unsigned int r = (x + 0x7fffu + ((x >> 16) & 1u)) >> 16;
    return (ushortT)r;
}

// ---- prep: W (128x128 f32, KxN) -> transposed + XOR-swizzled bf16 hi/lo images
// element (k,n) stored at  n*128 + (((k>>3) ^ (n&15))<<3) + (k&7)
__global__ __launch_bounds__(256) void prep_kernel(const float* __restrict__ W1,
                                                   const float* __restrict__ W2,
                                                   ushortT* __restrict__ wt) {
    const float* Wf = (blockIdx.x == 0) ? W1 : W2;
    ushortT* outh = wt + blockIdx.x * 32768;
    ushortT* outl = outh + 16384;
    int t = threadIdx.x;
#pragma unroll
    for (int i = 0; i < 16; i++) {
        int c = t + i * 256;            // 0..4095
        int k = c >> 5;
        int n0 = (c & 31) * 4;
        float4v w = *(const float4v*)(Wf + k * 128 + n0);
        int g = k >> 3, kk = k & 7;
#pragma unroll
        for (int j = 0; j < 4; j++) {
            int n = n0 + j;
            ushortT wh = f2bf(w[j]);
            ushortT wl = f2bf(w[j] - bf2f(wh));
            int addr = n * 128 + ((g ^ (n & 15)) << 3) + kk;
            outh[addr] = wh;
            outl[addr] = wl;
        }
    }
}

// ---- x (f32) -> bf16 plane, once per call ----
__global__ __launch_bounds__(256) void xbf_kernel(const float* __restrict__ x,
                                                  ushortT* __restrict__ xb) {
    int i = blockIdx.x * 256 + threadIdx.x;  // 8-elem group; grid exact (6250)
    float4v a = ((const float4v*)x)[2 * i];
    float4v b = ((const float4v*)x)[2 * i + 1];
    ushortT o[8];
#pragma unroll
    for (int j = 0; j < 4; j++) o[j] = f2bf(a[j]);
#pragma unroll
    for (int j = 0; j < 4; j++) o[4 + j] = f2bf(b[j]);
    ((uint4v*)xb)[i] = *(const uint4v*)o;
}

// ---- CSR build ----
__global__ __launch_bounds__(256) void hist_kernel(const int* __restrict__ dst,
                                                   int* __restrict__ counts) {
    int e = blockIdx.x * 256 + threadIdx.x;
    if (e < N_EDGES) atomicAdd(&counts[dst[e]], 1);
}

#define SCAN_BLOCKS 98  // 98*1024 >= 100000

__global__ __launch_bounds__(1024) void blockscan_kernel(const int* __restrict__ counts,
                                                         int* __restrict__ local,
                                                         int* __restrict__ bsums) {
    __shared__ int wsum[16];
    int tid = threadIdx.x, lane = tid & 63, wid = tid >> 6;
    int i = blockIdx.x * 1024 + tid;
    int v = (i < N_NODES) ? counts[i] : 0;
    int incl = v;
#pragma unroll
    for (int off = 1; off < 64; off <<= 1) {
        int u = __shfl_up(incl, off);
        if (lane >= off) incl += u;
    }
    if (lane == 63) wsum[wid] = incl;
    __syncthreads();
    if (wid == 0) {
        int s = (lane < 16) ? wsum[lane] : 0;
#pragma unroll
        for (int off = 1; off < 16; off <<= 1) {
            int u = __shfl_up(s, off);
            if (lane >= off) s += u;
        }
        if (lane < 16) wsum[lane] = s;
    }
    __syncthreads();
    int excl = ((wid == 0) ? 0 : wsum[wid - 1]) + incl - v;
    if (i < N_NODES) local[i] = excl;
    if (tid == 0) bsums[blockIdx.x] = wsum[15];
}

__global__ __launch_bounds__(1024) void fixup_kernel(const int* __restrict__ local,
                                                     const int* __restrict__ bsums,
                                                     int* __restrict__ offsets,
                                                     int* __restrict__ cursor) {
    __shared__ int sbase;
    int tid = threadIdx.x;
    if (tid < 64) {
        int s = 0;
        for (int j = tid; j < blockIdx.x; j += 64) s += bsums[j];
#pragma unroll
        for (int off = 32; off >= 1; off >>= 1) s += __shfl_xor(s, off);
        if (tid == 0) sbase = s;
    }
    __syncthreads();
    int base = sbase;
    int i = blockIdx.x * 1024 + tid;
    if (i < N_NODES) {
        int o = local[i] + base;
        offsets[i] = o;
        cursor[i] = o;
    }
    if (blockIdx.x == 0 && tid == 0) offsets[N_NODES] = N_EDGES;
}

__global__ __launch_bounds__(256) void fill_kernel(const int* __restrict__ src,
                                                   const int* __restrict__ dst,
                                                   int* __restrict__ cursor,
                                                   int* __restrict__ eidx) {
    int e = blockIdx.x * 256 + threadIdx.x;
    if (e < N_EDGES) {
        int pos = atomicAdd(&cursor[dst[e]], 1);
        eidx[pos] = src[e];
    }
}

// lgkm-only wait: vmcnt=63, expcnt=7, lgkmcnt=0 (gfx9 encoding)
#define LGKM0() __builtin_amdgcn_s_waitcnt(0xC07F)

// ---- fused GIN layer: out = act(relu((h + sum_nbr h) @ W1 + b1) @ W2 + b2) ----
// Aggregation is fused into the GEMM's A-fragment build: lane (quad,col16) owns
// dims [quad*8 + 32s, +8) of node row0 + r*16 + col16 and accumulates
// self + neighbors in f32 (ascending edge order == old agg_kernel => bit-identical),
// then RNE hi/lo-splits into ah/al MFMA fragments in-register. No z buffer, no agg
// dispatch. Gathers batched 4-deep (16 x 16B loads in flight), clamped index +
// predicated accumulate (no divergent branches around loads).
// Reads Hprev (previous layer, complete), writes only own 32 rows -> no race
// (ping-pong h buffers at the launcher).
// OUT 1: bf16 plane (stride 128) + relu.  OUT 2: f32 (stride 128), no relu.
template <int OUT>
__global__ __launch_bounds__(256, 2) void fused_kernel(const ushortT* __restrict__ Hprev,
                                                       const int* __restrict__ offs,
                                                       const int* __restrict__ eidx,
                                                       const ushortT* __restrict__ w1HL,
                                                       const ushortT* __restrict__ w2HL,
                                                       const float* __restrict__ b1,
                                                       const float* __restrict__ b2,
                                                       void* __restrict__ out) {
    __shared__ ushortT SH[40960];  // 80KB: W image [0,32768), transpose scratch [32768,40960)

    int t = threadIdx.x, lane = t & 63, wid = t >> 6;
    int unit = blockIdx.x * 4 + wid;  // 32-row unit; 3125 total
    int quad = lane >> 4, col16 = lane & 15;
    bool active = unit < (N_NODES / 32);
    int row0 = unit * 32;

    float bia1[8], bia2[8];
#pragma unroll
    for (int n = 0; n < 8; n++) {
        bia1[n] = b1[n * 16 + col16];
        bia2[n] = b2[n * 16 + col16];
    }

    // stage W1 images: coalesced b128
#pragma unroll
    for (int i = 0; i < 16; i++) {
        int idx = (t + i * 256) * 8;
        *(uint4v*)&SH[idx] = *(const uint4v*)&w1HL[idx];
    }
    __syncthreads();

    // ---- fused aggregation -> A fragments (ah/al) ----
    short8 ah[4][2], al[4][2];
    if (active) {
#pragma unroll
        for (int r = 0; r < 2; r++) {
            int v = row0 + r * 16 + col16;
            int beg = offs[v], end = offs[v + 1];
            int cnt = end - beg;
            const ushortT* hq = Hprev + (size_t)v * DIM + quad * 8;
            float accf[4][8];
#pragma unroll
            for (int s = 0; s < 4; s++) {  // self term first (same order as agg_kernel)
                short8 x = *(const short8*)(hq + s * 32);
                uint4v u = __builtin_bit_cast(uint4v, x);
#pragma unroll
                for (int p = 0; p < 4; p++) {
                    accf[s][2 * p]     = bflo(u[p]);
                    accf[s][2 * p + 1] = bfhi(u[p]);
                }
            }
            for (int base = 0; base < cnt; base += 4) {
                int idx[4];
#pragma unroll
                for (int jj = 0; jj < 4; jj++) {
                    int q = base + jj;
                    if (q > cnt - 1) q = cnt - 1;  // clamp: dup loads hit L1
                    idx[jj] = eidx[beg + q];
                }
                short8 vv[4][4];
#pragma unroll
                for (int jj = 0; jj < 4; jj++) {
                    const ushortT* hu = Hprev + (size_t)idx[jj] * DIM + quad * 8;
#pragma unroll
                    for (int s = 0; s < 4; s++) vv[jj][s] = *(const short8*)(hu + s * 32);
                }
                int rem = cnt - base;  // per-lane predicate
#pragma unroll
                for (int jj = 0; jj < 4; jj++)
                    if (jj < rem) {
#pragma unroll
                        for (int s = 0; s < 4; s++) {
                            uint4v u = __builtin_bit_cast(uint4v, vv[jj][s]);
#pragma unroll
                            for (int p = 0; p < 4; p++) {
                                accf[s][2 * p]     += bflo(u[p]);
                                accf[s][2 * p + 1] += bfhi(u[p]);
                            }
                        }
                    }
            }
            // RNE hi/lo split -> MFMA A fragments (identical to old z hi/lo planes)
#pragma unroll
            for (int s = 0; s < 4; s++) {
                ushortT oh[8], ol[8];
#pragma unroll
                for (int e = 0; e < 8; e++) {
                    ushortT hi = f2bf(accf[s][e]);
                    oh[e] = hi;
                    ol[e] = f2bf(accf[s][e] - bf2f(hi));
                }
                ah[s][r] = *(const short8*)oh;
                al[s][r] = *(const short8*)ol;
            }
        }
    }

    // ---- GEMM1: acc = z @ W1 (3-term bf16 split) ----
    float4v acc[2][8];
    if (active) {
#pragma unroll
        for (int r = 0; r < 2; r++)
#pragma unroll
            for (int n = 0; n < 8; n++) acc[r][n] = (float4v)0.0f;
#pragma unroll
        for (int s = 0; s < 4; s++) {
            short8 bh[8], bl[8];
#pragma unroll
            for (int n = 0; n < 8; n++) {
                int addr = (n * 16 + col16) * 128 + (((s * 4 + quad) ^ col16) << 3);
                bh[n] = *(const short8*)&SH[addr];
                bl[n] = *(const short8*)&SH[16384 + addr];
            }
            __builtin_amdgcn_s_setprio(1);
#pragma unroll
            for (int r = 0; r < 2; r++)
#pragma unroll
                for (int n = 0; n < 8; n++) {
                    acc[r][n] = __builtin_amdgcn_mfma_f32_16x16x32_bf16(ah[s][r], bh[n], acc[r][n], 0, 0, 0);
                    acc[r][n] = __builtin_amdgcn_mfma_f32_16x16x32_bf16(al[s][r], bh[n], acc[r][n], 0, 0, 0);
                    acc[r][n] = __builtin_amdgcn_mfma_f32_16x16x32_bf16(ah[s][r], bl[n], acc[r][n], 0, 0, 0);
                }
            __builtin_amdgcn_s_setprio(0);
        }
    }
    __syncthreads();  // all waves done reading W1

    // restage W2 over the dead W1 region (L2-hit, 64KB/block)
#pragma unroll
    for (int i = 0; i < 16; i++) {
        int idx = (t + i * 256) * 8;
        *(uint4v*)&SH[idx] = *(const uint4v*)&w2HL[idx];
    }
    __syncthreads();

    float4v acc2[2][8];
    if (active) {
#pragma unroll
        for (int r = 0; r < 2; r++)
#pragma unroll
            for (int n = 0; n < 8; n++) acc2[r][n] = (float4v)0.0f;
        ushortT* scr = &SH[32768 + wid * 2048];  // 32 rows x 64 ushorts, XOR-swizzled
#pragma unroll
        for (int s2 = 0; s2 < 4; s2++) {
            LGKM0();  // WAR: prior s2's scratch reads landed before overwrite
            // transpose-write hid cols [32*s2, 32*s2+32): bias+relu, RNE hi/lo split
#pragma unroll
            for (int r = 0; r < 2; r++)
#pragma unroll
                for (int h = 0; h < 2; h++) {
                    int n = s2 * 2 + h;
#pragma unroll
                    for (int i = 0; i < 4; i++) {
                        float v = acc[r][n][i] + bia1[n];
                        v = v > 0.0f ? v : 0.0f;
                        int row = r * 16 + quad * 4 + i;
                        ushortT hi = f2bf(v);
                        ushortT lo = f2bf(v - bf2f(hi));
                        int c8 = h * 2 + (col16 >> 3);
                        int base = row * 64 + (col16 & 7);
                        scr[base + ((c8 ^ (row & 7)) << 3)]       = hi;
                        scr[base + (((4 + c8) ^ (row & 7)) << 3)] = lo;
                    }
                }
            LGKM0();  // writes visible before readback (per-wave scratch)
            short8 a2h[2], a2l[2];
#pragma unroll
            for (int r = 0; r < 2; r++) {
                int rrow = r * 16 + col16;
                a2h[r] = *(const short8*)&scr[rrow * 64 + ((quad ^ (rrow & 7)) << 3)];
                a2l[r] = *(const short8*)&scr[rrow * 64 + (((4 + quad) ^ (rrow & 7)) << 3)];
            }
            short8 bh[8], bl[8];
#pragma unroll
            for (int n = 0; n < 8; n++) {
                int addr = (n * 16 + col16) * 128 + (((s2 * 4 + quad) ^ col16) << 3);
                bh[n] = *(const short8*)&SH[addr];
                bl[n] = *(const short8*)&SH[16384 + addr];
            }
            __builtin_amdgcn_s_setprio(1);
#pragma unroll
            for (int r = 0; r < 2; r++)
#pragma unroll
                for (int n = 0; n < 8; n++) {
                    acc2[r][n] = __builtin_amdgcn_mfma_f32_16x16x32_bf16(a2h[r], bh[n], acc2[r][n], 0, 0, 0);
                    acc2[r][n] = __builtin_amdgcn_mfma_f32_16x16x32_bf16(a2l[r], bh[n], acc2[r][n], 0, 0, 0);
                    acc2[r][n] = __builtin_amdgcn_mfma_f32_16x16x32_bf16(a2h[r], bl[n], acc2[r][n], 0, 0, 0);
                }
            __builtin_amdgcn_s_setprio(0);
        }
    }
    __syncthreads();  // W region dead after all waves' K-loops
    if (!active) return;

    // epilogue: C/D layout col=lane&15 (within n-block), row=quad*4+i.
    // Two 16-row passes through per-wave LDS scratch -> coalesced stores.
#pragma unroll
    for (int r = 0; r < 2; r++) {
        if constexpr (OUT == 1) {
            ushortT* tr = &SH[wid * 2304];
#pragma unroll
            for (int n = 0; n < 8; n++)
#pragma unroll
                for (int i = 0; i < 4; i++) {
                    float v = acc2[r][n][i] + bia2[n];
                    v = v > 0.0f ? v : 0.0f;
                    tr[(quad * 4 + i) * 136 + n * 16 + col16] = f2bf(v);
                }
            LGKM0();
#pragma unroll
            for (int p = 0; p < 4; p++) {
                int row = p * 4 + (lane >> 4);
                int seg = lane & 15;
                uint4v val = *(const uint4v*)&tr[row * 136 + seg * 8];
                *(uint4v*)((ushortT*)out + (size_t)(row0 + r * 16 + row) * 128 + seg * 8) = val;
            }
        } else {
            float* trf = (float*)&SH[wid * 4352];  // stride 132 floats
#pragma unroll
            for (int n = 0; n < 8; n++)
#pragma unroll
                for (int i = 0; i < 4; i++)
                    trf[(quad * 4 + i) * 132 + n * 16 + col16] = acc2[r][n][i] + bia2[n];
            LGKM0();
#pragma unroll
            for (int p = 0; p < 8; p++) {
                int row = p * 2 + (lane >> 5);
                int seg = lane & 31;
                float4v val = *(const float4v*)&trf[row * 132 + seg * 4];
                *(float4v*)((float*)out + (size_t)(row0 + r * 16 + row) * 128 + seg * 4) = val;
            }
        }
        if (r == 0) LGKM0();  // WAR guard before pass 2 overwrite
    }
}

extern "C" void kernel_launch(void* const* d_in, const int* in_sizes, int n_in,
                              void* d_out, int out_size, void* d_ws, size_t ws_size,
                              hipStream_t stream) {
    const float* x  = (const float*)d_in[0];
    const int* src  = (const int*)d_in[1];
    const int* dst  = (const int*)d_in[2];
    const float* W1 = (const float*)d_in[3];
    const float* b1 = (const float*)d_in[4];
    const float* W2 = (const float*)d_in[5];
    const float* b2 = (const float*)d_in[6];

    char* ws = (char*)d_ws;
    ushortT* wt     = (ushortT*)ws;                        // 128 KB: W1H|W1L|W2H|W2L (swizzled)
    int*     offs   = (int*)(ws + 131072);                 // 100001 ints
    int*     cursor = (int*)(ws + 531456);                 // 100000 ints
    int*     eidx   = (int*)(ws + 931456);                 // 600000 ints
    int*     local  = (int*)(ws + 3331456);                // 100000 ints
    int*     bsums  = (int*)(ws + 3731456);                // 98 ints
    ushortT* xbf    = (ushortT*)(ws + 3731968);            // 25.6 MB bf16 x
    ushortT* h1     = (ushortT*)(ws + 3731968 + 25600000); // 25.6 MB bf16 h (layer0 out)
    ushortT* h2     = (ushortT*)(ws + 3731968 + 51200000); // 25.6 MB bf16 h (layer1 out)
    // total ~80.5 MB

    const ushortT* w1 = wt;          // WH at +0, WL at +16384
    const ushortT* w2 = wt + 32768;  // WH at +0, WL at +16384

    dim3 blk(256);
    const int gEdge = (N_EDGES + 255) / 256;    // 2344
    const int gFus  = (N_NODES / 32 + 3) / 4;   // 782 (3125 32-row units)
    const int gXbf  = N_NODES * DIM / 8 / 256;  // 6250 exact

    prep_kernel<<<2, blk, 0, stream>>>(W1, W2, wt);
    xbf_kernel<<<gXbf, blk, 0, stream>>>(x, xbf);
    hipMemsetAsync(cursor, 0, N_NODES * sizeof(int), stream);
    hist_kernel<<<gEdge, blk, 0, stream>>>(dst, cursor);
    blockscan_kernel<<<SCAN_BLOCKS, 1024, 0, stream>>>(cursor, local, bsums);
    fixup_kernel<<<SCAN_BLOCKS, 1024, 0, stream>>>(local, bsums, offs, cursor);
    fill_kernel<<<gEdge, blk, 0, stream>>>(src, dst, cursor, eidx);

    // layer 0: gather from xbf, write h1
    fused_kernel<1><<<gFus, blk, 0, stream>>>(xbf, offs, eidx, w1, w2, b1, b2, h1);
    // layer 1: gather from h1, write h2 (ping-pong: no gather/write race)
    fused_kernel<1><<<gFus, blk, 0, stream>>>(h1, offs, eidx, w1, w2, b1, b2, h2);
    // layer 2: gather from h2, write f32 d_out (no relu)
    fused_kernel<2><<<gFus, blk, 0, stream>>>(h2, offs, eidx, w1, w2, b1, b2, (float*)d_out);
}